// Round 3
// baseline (106.182 us; speedup 1.0000x reference)
//
#include <hip/hip_runtime.h>

// Problem constants (GATLayer): B=4, N=2048, TOKEN_DIM=512, HIDDEN=128
// IO dtype: fp32. Internally: bf16 MFMA with fp32 accumulate.
// v10: three dispatches.
//   k_prep : fc_w fp32 -> bf16 (RTNE) once into workspace.
//   k_fused: back to v8 shape (512 thr / 16-row tiles -> 2 blocks/CU barrier
//            overlap), B-frags direct bf16 loads from Wb.
//   k_attn : produce INTERLEAVED into the consume s-loop (2 exp-elems per
//            k-step) so exp VALU fills MFMA dep-chain stalls within a wave;
//            ds_writes of next chunk happen after all reads of current chunk.
// All fp32->bf16 via manual RTNE f2bf (validated in passing runs).
#define NB      4
#define NTOK    2048
#define TOKDIM  512
#define HID     128
#define NROWS   (NB * NTOK)      // 8192
#define LN_EPS  1e-5f
#define NEG_SLOPE 0.01f

typedef short bf16x8 __attribute__((ext_vector_type(8)));   // 8 bf16 in 4 VGPRs
typedef float f32x4  __attribute__((ext_vector_type(4)));

static __device__ __forceinline__ unsigned short f2bf(float f) {
    union { float f; unsigned int i; } v; v.f = f;
    unsigned int i = v.i;
    i += 0x7FFFu + ((i >> 16) & 1u);   // round-to-nearest-even
    return (unsigned short)(i >> 16);
}

// ---------------------------------------------------------------------------
// k_prep: convert fc_w (128x512 fp32) -> bf16 once. 64 blocks x 256 thr.
// ---------------------------------------------------------------------------
__global__ __launch_bounds__(256) void k_prep(const float* __restrict__ W,
                                              unsigned short* __restrict__ Wb) {
    const int g = blockIdx.x * 256 + threadIdx.x;   // 0..16383
    float4 v = *(const float4*)(W + (size_t)g * 4);
    ushort4 o;
    o.x = f2bf(v.x); o.y = f2bf(v.y); o.z = f2bf(v.z); o.w = f2bf(v.w);
    *(ushort4*)(Wb + (size_t)g * 4) = o;
}

// ---------------------------------------------------------------------------
// k_fused (v8 shape): per 16-row tile: FC (MFMA, A from LDS-staged bf16 X,
// B from pre-converted bf16 Wb) + bias + LayerNorm + scores + transposed hT.
// Grid 512 blocks x 512 thr (8 waves, ~25KB LDS -> 2 blocks/CU). Wave wv owns
// n-cols [wv*16,+16).
// ---------------------------------------------------------------------------
__global__ __launch_bounds__(512) void k_fused(const float* __restrict__ X,
                                               const unsigned short* __restrict__ Wb,
                                               const float* __restrict__ fcb,
                                               const float* __restrict__ attnw,
                                               const float* __restrict__ attnb,
                                               const float* __restrict__ lng,
                                               const float* __restrict__ lnb,
                                               unsigned short* __restrict__ hT,
                                               float* __restrict__ srow,
                                               float* __restrict__ cc) {
    __shared__ char smem[16640 + 16 * 132 * 4];
    unsigned short* ldsX = (unsigned short*)smem;            // [16][520]
    unsigned short* ldsT = (unsigned short*)smem;            // [128][20] (reuse)
    float* hfull = (float*)(smem + 16640);                   // [16][132]

    const int tid  = threadIdx.x;
    const int wv   = tid >> 6;
    const int lane = tid & 63;
    const int m    = lane & 15;
    const int q    = lane >> 4;
    const int rowbase = blockIdx.x * 16;
    const int nbase   = wv * 16;

    // ---- phase A: stage X tile -> LDS bf16 (each element converted once)
    {
        const int r  = tid >> 5;            // 0..15
        const int c0 = (tid & 31) * 16;     // 0..496
        const float* xp = X + (size_t)(rowbase + r) * TOKDIM + c0;
        bf16x8 v0, v1;
#pragma unroll
        for (int u = 0; u < 8; ++u) v0[u] = (short)f2bf(xp[u]);
#pragma unroll
        for (int u = 0; u < 8; ++u) v1[u] = (short)f2bf(xp[8 + u]);
        *(bf16x8*)&ldsX[r * 520 + c0]     = v0;
        *(bf16x8*)&ldsX[r * 520 + c0 + 8] = v1;
    }
    __syncthreads();

    // ---- phase B: MFMA. A[m][k] from ldsX, B[k][n]=W[n][k] direct bf16.
    const unsigned short* wp = Wb + (size_t)(nbase + m) * TOKDIM + q * 8;
    f32x4 acc = {0.f, 0.f, 0.f, 0.f};
#pragma unroll
    for (int kk = 0; kk < TOKDIM / 32; ++kk) {
        bf16x8 a = *(const bf16x8*)&ldsX[m * 520 + kk * 32 + q * 8];
        bf16x8 b = *(const bf16x8*)(wp + kk * 32);
        acc = __builtin_amdgcn_mfma_f32_16x16x32_bf16(a, b, acc, 0, 0, 0);
    }

    // ---- phase C: acc (+fc_b) -> hfull LDS
    {
        const float bias = fcb[nbase + m];
#pragma unroll
        for (int r = 0; r < 4; ++r)
            hfull[(q * 4 + r) * 132 + nbase + m] = acc[r] + bias;
    }
    __syncthreads();   // hfull ready; ldsX dead (safe to reuse as ldsT)

    // ---- phase D: LN + scores; write bf16 h into ldsT transposed
    {
        const int r   = tid >> 5;           // row 0..15
        const int l32 = tid & 31;
        const int c0  = l32 * 4;
        float4 hv = *(const float4*)&hfull[r * 132 + c0];
        float v[4] = {hv.x, hv.y, hv.z, hv.w};

        float s  = v[0] + v[1] + v[2] + v[3];
        float ss = v[0]*v[0] + v[1]*v[1] + v[2]*v[2] + v[3]*v[3];
#pragma unroll
        for (int d = 1; d < 32; d <<= 1) {
            s  += __shfl_xor(s,  d, 64);
            ss += __shfl_xor(ss, d, 64);
        }
        float mu  = s * (1.f / HID);
        float var = ss * (1.f / HID) - mu * mu;
        float rs  = rsqrtf(var + LN_EPS);

        float n[4], sr = 0.f, sc = 0.f;
#pragma unroll
        for (int k = 0; k < 4; ++k) {
            n[k] = lng[c0 + k] * (v[k] - mu) * rs + lnb[c0 + k];
            sr += n[k] * attnw[c0 + k];
            sc += n[k] * attnw[HID + c0 + k];
            ldsT[(c0 + k) * 20 + r] = f2bf(n[k]);
        }
#pragma unroll
        for (int d = 1; d < 32; d <<= 1) {
            sr += __shfl_xor(sr, d, 64);
            sc += __shfl_xor(sc, d, 64);
        }
        if (l32 == 0) {
            int grow = rowbase + r;
            srow[grow] = sr;
            cc[grow]   = sc + attnb[0];
        }
    }
    __syncthreads();

    // ---- phase E: coalesced hT write. thread t: d = t>>2, 4 j's.
    {
        const int d  = tid >> 2;
        const int j4 = (tid & 3) * 4;
        const int b    = blockIdx.x >> 7;          // 128 blocks per batch
        const int jblk = (blockIdx.x & 127) * 16;
        ushort4 o;
        o.x = ldsT[d * 20 + j4 + 0];
        o.y = ldsT[d * 20 + j4 + 1];
        o.z = ldsT[d * 20 + j4 + 2];
        o.w = ldsT[d * 20 + j4 + 3];
        *(ushort4*)(hT + ((size_t)(b * HID + d)) * NTOK + jblk + j4) = o;
    }
}

// ---------------------------------------------------------------------------
// k_attn v8: 256 blocks x 512 thr (8 waves); block owns 32 i-rows; j in 8
// chunks of 256. Validated mappings unchanged. Scheduling: produce of chunk
// ch+1 is INTERLEAVED into the 8 consume k-steps of chunk ch (2 exp-elements
// per step), so exp VALU fills MFMA dep-chain stalls within the wave. The
// produced fragment is held in regs (v0,v1) and written to LDS after all
// reads of the current chunk.
//  RAW: consume(ch+1) reads pP[(ch+1)&1] after barrier(ch).     -> safe
//  WAR: produce(ch+1) writes pP[(ch+1)&1]; its prior readers ran
//       before barrier(ch-1).                                   -> safe
// ---------------------------------------------------------------------------
static __device__ __forceinline__ void produce_chunk(
        unsigned short* __restrict__ dst,   // &pP[buf][i_loc][jseg]
        float ci, float4 s0, float4 s1, float4 s2, float4 s3,
        float& lsum) {
    float sv[16] = {s0.x, s0.y, s0.z, s0.w, s1.x, s1.y, s1.z, s1.w,
                    s2.x, s2.y, s2.z, s2.w, s3.x, s3.y, s3.z, s3.w};
    bf16x8 v0, v1;
#pragma unroll
    for (int u = 0; u < 8; ++u) {
        float z = ci + sv[u];
        z = fmaxf(z, NEG_SLOPE * z);
        float p = __expf(z);
        lsum += p;
        v0[u] = (short)f2bf(p);
    }
#pragma unroll
    for (int u = 0; u < 8; ++u) {
        float z = ci + sv[8 + u];
        z = fmaxf(z, NEG_SLOPE * z);
        float p = __expf(z);
        lsum += p;
        v1[u] = (short)f2bf(p);
    }
    *(bf16x8*)dst       = v0;
    *(bf16x8*)(dst + 8) = v1;
}

__global__ __launch_bounds__(512) void k_attn(const unsigned short* __restrict__ hT,
                                              const float* __restrict__ srow,
                                              const float* __restrict__ cc,
                                              float* __restrict__ out) {
    __shared__ unsigned short pP[2][32][264];   // 2 x 16896 B, +8 pad
    __shared__ float pDen[32][16];              // 2 KB
    __shared__ float denv[32];

    const int tid  = threadIdx.x;
    const int wv   = tid >> 6;
    const int lane = tid & 63;
    const int m    = lane & 15;
    const int q    = lane >> 4;
    const int rowbase = blockIdx.x * 32;     // global row base
    const int b    = blockIdx.x >> 6;        // 64 blocks per batch
    const int dbase = wv * 16;

    // producer indices
    const int i_loc = tid >> 4;              // 0..31
    const int jseg  = (tid & 15) * 16;       // 0..240
    const float ci  = cc[rowbase + i_loc];
    const float* sp = srow + (size_t)b * NTOK + jseg;

    // consumer B pointer
    const unsigned short* hp =
        hT + ((size_t)(b * HID + dbase + m)) * NTOK + q * 8;

    f32x4 acc0 = {0.f, 0.f, 0.f, 0.f};      // i-subtile 0 (rows 0..15)
    f32x4 acc1 = {0.f, 0.f, 0.f, 0.f};      // i-subtile 1 (rows 16..31)
    float lsum = 0.f;

    // ---- prologue: srow(0)+B(0) loads; produce chunk 0; load srow(1)
    float4 s0 = *(const float4*)(sp);
    float4 s1 = *(const float4*)(sp + 4);
    float4 s2 = *(const float4*)(sp + 8);
    float4 s3 = *(const float4*)(sp + 12);
    bf16x8 bcur[8];
#pragma unroll
    for (int s = 0; s < 8; ++s) bcur[s] = *(const bf16x8*)(hp + s * 32);

    produce_chunk(&pP[0][i_loc][jseg], ci, s0, s1, s2, s3, lsum);

    float4 n0, n1, n2, n3;
    {
        const float* spn = sp + 256;
        n0 = *(const float4*)(spn);
        n1 = *(const float4*)(spn + 4);
        n2 = *(const float4*)(spn + 8);
        n3 = *(const float4*)(spn + 12);
    }

    __syncthreads();   // pP[0] ready

// one consume k-step (2 ds_read + 2 MFMA) fused with 2 produce elements of
// chunk ch+1 taken from srow regs (f0,f1); results land in V[e], V[e+1].
#define ASTEP(s, f0, f1, V, e)                                                  \
    {                                                                           \
        bf16x8 a0 = *(const bf16x8*)&pP[ch & 1][m][(s) * 32 + q * 8];           \
        bf16x8 a1 = *(const bf16x8*)&pP[ch & 1][16 + m][(s) * 32 + q * 8];      \
        acc0 = __builtin_amdgcn_mfma_f32_16x16x32_bf16(a0, bcur[s], acc0, 0, 0, 0); \
        acc1 = __builtin_amdgcn_mfma_f32_16x16x32_bf16(a1, bcur[s], acc1, 0, 0, 0); \
        if (ch < 7) {                                                           \
            float z0 = ci + (f0); z0 = fmaxf(z0, NEG_SLOPE * z0);               \
            float p0 = __expf(z0); lsum += p0;                                  \
            float z1 = ci + (f1); z1 = fmaxf(z1, NEG_SLOPE * z1);               \
            float p1 = __expf(z1); lsum += p1;                                  \
            V[e]     = (short)f2bf(p0);                                         \
            V[e + 1] = (short)f2bf(p1);                                         \
        }                                                                       \
    }

#pragma unroll
    for (int ch = 0; ch < 8; ++ch) {
        // ---- prefetch B(ch+1) early: full s-loop covers its latency
        bf16x8 bnxt[8];
        if (ch < 7) {
            const unsigned short* hpn = hp + (ch + 1) * 256;
#pragma unroll
            for (int s = 0; s < 8; ++s) bnxt[s] = *(const bf16x8*)(hpn + s * 32);
        }

        // ---- 8 fused k-steps: MFMA(chunk ch) + produce(chunk ch+1)
        bf16x8 v0, v1;
        ASTEP(0, n0.x, n0.y, v0, 0)
        ASTEP(1, n0.z, n0.w, v0, 2)
        ASTEP(2, n1.x, n1.y, v0, 4)
        ASTEP(3, n1.z, n1.w, v0, 6)
        ASTEP(4, n2.x, n2.y, v1, 0)
        ASTEP(5, n2.z, n2.w, v1, 2)
        ASTEP(6, n3.x, n3.y, v1, 4)
        ASTEP(7, n3.z, n3.w, v1, 6)

        if (ch < 7) {
            // ---- stage produced fragment (after all reads of chunk ch)
            *(bf16x8*)&pP[(ch + 1) & 1][i_loc][jseg]     = v0;
            *(bf16x8*)&pP[(ch + 1) & 1][i_loc][jseg + 8] = v1;
            // ---- load srow(ch+2) for next iteration's produce
            if (ch < 6) {
                const float* spn = sp + (ch + 2) * 256;
                n0 = *(const float4*)(spn);
                n1 = *(const float4*)(spn + 4);
                n2 = *(const float4*)(spn + 8);
                n3 = *(const float4*)(spn + 12);
            }
        }

        __syncthreads();   // pP[(ch+1)&1] complete; chunk ch fully consumed

        if (ch < 7) {
#pragma unroll
            for (int s = 0; s < 8; ++s) bcur[s] = bnxt[s];
        }
    }
#undef ASTEP

    // ---- denominators: thread covered (i_loc, jseg window) across chunks
    pDen[i_loc][tid & 15] = lsum;
    __syncthreads();
    if (tid < 32) {
        float d = 0.f;
#pragma unroll
        for (int k = 0; k < 16; ++k) d += pDen[tid][k];
        denv[tid] = 1.f / d;
    }
    __syncthreads();

    // ---- epilogue: out[row=i][col=d], validated C/D mapping
#pragma unroll
    for (int r = 0; r < 4; ++r) {
        int r0 = q * 4 + r;
        out[(size_t)(rowbase + r0) * HID + dbase + m]      = acc0[r] * denv[r0];
        out[(size_t)(rowbase + 16 + r0) * HID + dbase + m] = acc1[r] * denv[16 + r0];
    }
}

// ---------------------------------------------------------------------------
extern "C" void kernel_launch(void* const* d_in, const int* in_sizes, int n_in,
                              void* d_out, int out_size, void* d_ws, size_t ws_size,
                              hipStream_t stream) {
    const float* X     = (const float*)d_in[0]; // token_embedding [4,2048,512]
    const float* W     = (const float*)d_in[1]; // fc_w [128,512]
    const float* fcb   = (const float*)d_in[2]; // fc_b [128]
    const float* attnw = (const float*)d_in[3]; // attn_w [1,256]
    const float* attnb = (const float*)d_in[4]; // attn_b [1]
    const float* lng   = (const float*)d_in[5]; // ln_g [128]
    const float* lnb   = (const float*)d_in[6]; // ln_b [128]
    float* out = (float*)d_out;                 // h_prime [4,2048,128] fp32

    char* ws = (char*)d_ws;
    unsigned short* hT   = (unsigned short*)ws;                          // 2 MB
    float*          srow = (float*)(ws + 2u * 1024 * 1024);              // 32 KB
    float*          cchd = (float*)(ws + 2u * 1024 * 1024 + 32u * 1024); // 32 KB
    unsigned short* Wb   = (unsigned short*)(ws + 2u * 1024 * 1024 + 64u * 1024); // 128 KB

    k_prep <<<64, 256, 0, stream>>>(W, Wb);
    k_fused<<<NROWS / 16, 512, 0, stream>>>(X, Wb, fcb, attnw, attnb, lng, lnb,
                                            hT, srow, cchd);
    k_attn <<<NROWS / 32, 512, 0, stream>>>(hT, srow, cchd, out);
}